// Round 2
// baseline (1654.573 us; speedup 1.0000x reference)
//
#include <hip/hip_runtime.h>
#include <hip/hip_fp16.h>

typedef _Float16 f16;
typedef f16 f16x8 __attribute__((ext_vector_type(8)));
typedef float f32x4 __attribute__((ext_vector_type(4)));

#define NPIX 16384
#define DDIM 256
#define KCB  8192
#define KCAT 768
#define LOG2E 1.44269504088896340736f

// ---- async global->LDS (16B per lane, lane-contiguous LDS dest) ----
__device__ __forceinline__ void lds_async16(const void* g, void* l) {
    __builtin_amdgcn_global_load_lds(
        (const __attribute__((address_space(1))) unsigned int*)g,
        (__attribute__((address_space(3))) unsigned int*)l,
        16, 0, 0);
}

#define VM0  asm volatile("s_waitcnt vmcnt(0)" ::: "memory")
#define LG0  asm volatile("s_waitcnt lgkmcnt(0)" ::: "memory")
#define BAR  { __builtin_amdgcn_sched_barrier(0); __builtin_amdgcn_s_barrier(); __builtin_amdgcn_sched_barrier(0); }

// ---- init scratch (ws re-poisoned 0xAA before every call) ----
__global__ void init_k(float* gsum, unsigned long long* gmin) {
    int i = blockIdx.x * 256 + threadIdx.x;
    if (i < NPIX) { gsum[i] = 0.f; gmin[i] = ~0ULL; }
}

// ---- split x into fp16 hi/lo, packed [xh | xl | xh] per row (K=768) ----
// x pre-scaled by 2*log2(e): MFMA yields log2-domain logits directly.
__global__ void prep_x(const float* __restrict__ x, f16* __restrict__ Acat) {
    int p = blockIdx.x, d = threadIdx.x;
    float v = x[p * DDIM + d] * (2.0f * LOG2E);
    f16 h = (f16)v;
    f16 lo = (f16)(v - (float)h);
    Acat[p * KCAT + d]        = h;
    Acat[p * KCAT + 256 + d]  = lo;
    Acat[p * KCAT + 512 + d]  = h;
}

// ---- split codebook, packed [ch | ch | cl]; c2 = ||c||^2 * log2(e) ----
__global__ void prep_c(const float* __restrict__ cb, f16* __restrict__ Bcat,
                       float* __restrict__ c2) {
    int k = blockIdx.x, d = threadIdx.x;
    float v = cb[k * DDIM + d];
    f16 h = (f16)v;
    f16 lo = (f16)(v - (float)h);
    Bcat[k * KCAT + d]       = h;
    Bcat[k * KCAT + 256 + d] = h;
    Bcat[k * KCAT + 512 + d] = lo;
    float v2 = v * v;
    #pragma unroll
    for (int m = 32; m; m >>= 1) v2 += __shfl_xor(v2, m);
    __shared__ float ws4[4];
    if ((threadIdx.x & 63) == 0) ws4[threadIdx.x >> 6] = v2;
    __syncthreads();
    if (threadIdx.x == 0) c2[k] = (ws4[0] + ws4[1] + ws4[2] + ws4[3]) * LOG2E;
}

// ---- transpose ch into chT[256][8192] f16 for gemm2 B-operand ----
__global__ void transpose_c(const f16* __restrict__ Bcat, f16* __restrict__ chT) {
    __shared__ f16 tile[64][68];
    int k0 = blockIdx.x * 64, d0 = blockIdx.y * 64;
    #pragma unroll
    for (int i = 0; i < 16; ++i) {
        int idx = i * 256 + threadIdx.x;
        int kl = idx >> 6, dl = idx & 63;
        tile[kl][dl] = Bcat[(k0 + kl) * KCAT + d0 + dl];
    }
    __syncthreads();
    #pragma unroll
    for (int i = 0; i < 16; ++i) {
        int idx = i * 256 + threadIdx.x;
        int dl = idx >> 6, kl = idx & 63;
        chT[(size_t)(d0 + dl) * KCB + k0 + kl] = tile[kl][dl];
    }
}

// ---- GEMM1: u = exp2(acc - c2' + noise*log2e) + row-sum + argmin ----
// v3: SWAPPED mfma operands -> acc[i][j] holds D[cb=i*16+q4*4+r][pix=j*16+fr].
// Per lane the 4 regs are 4 CONSECUTIVE codebook cols -> all epilogue traffic
// (noise rd, U wr, c2 rd) is float4-vectorized; reduction = 2 shfl_xor.
__global__ __launch_bounds__(256) void gemm1(
    const f16* __restrict__ A, const f16* __restrict__ B,
    const float* __restrict__ c2, const float* __restrict__ noise,
    float* __restrict__ U, float* __restrict__ gsum,
    unsigned long long* __restrict__ gmin)
{
    __shared__ f16 As0[128 * 32];
    __shared__ f16 As1[128 * 32];
    __shared__ f16 Bs0[128 * 32];
    __shared__ f16 Bs1[128 * 32];
    __shared__ float lsum[128];
    __shared__ unsigned long long lmin[128];

    const int tid = threadIdx.x;
    const int lane = tid & 63, wid = tid >> 6;
    const int bm = blockIdx.y, bn = blockIdx.x;
    const int wm = (wid & 1) * 64, wn = (wid >> 1) * 64;
    const int fr = lane & 15, q4 = lane >> 4;
    const int fk = q4 * 8;

    if (tid < 128) { lsum[tid] = 0.f; lmin[tid] = ~0ULL; }

    const f32x4 z = {0.f, 0.f, 0.f, 0.f};
    f32x4 acc[4][4];            // [i=codebook frag][j=pixel frag]
    #pragma unroll
    for (int i = 0; i < 4; ++i)
        #pragma unroll
        for (int j = 0; j < 4; ++j) acc[i][j] = z;

    // staging: thread t owns 16B chunk q -> row q/64, half-offset (q%64)/2
    const int q = tid * 16;
    const int sr = q >> 6;
    const int sk = (q & 63) >> 1;
    const f16* Ab = A + (size_t)(bm * 128 + sr) * KCAT + sk;
    const f16* Bb = B + (size_t)(bn * 128 + sr) * KCAT + sk;

    auto stage = [&](int t, char* asd, char* bsd) {
        const int k0 = t * 32;
        lds_async16(Ab + k0,             asd + q);
        lds_async16(Ab + 64 * KCAT + k0, asd + q + 4096);
        lds_async16(Bb + k0,             bsd + q);
        lds_async16(Bb + 64 * KCAT + k0, bsd + q + 4096);
    };
    auto compute = [&](const f16* as, const f16* bs) {
        f16x8 cbf[4], pxf[4];
        #pragma unroll
        for (int i = 0; i < 4; ++i)
            cbf[i] = *(const f16x8*)(bs + (wn + i * 16 + fr) * 32 + fk);
        #pragma unroll
        for (int j = 0; j < 4; ++j)
            pxf[j] = *(const f16x8*)(as + (wm + j * 16 + fr) * 32 + fk);
        #pragma unroll
        for (int i = 0; i < 4; ++i)
            #pragma unroll
            for (int j = 0; j < 4; ++j)
                acc[i][j] = __builtin_amdgcn_mfma_f32_16x16x32_f16(cbf[i], pxf[j], acc[i][j], 0, 0, 0);
    };

    stage(0, (char*)As0, (char*)Bs0);
    VM0; BAR;
    for (int t = 0; t < 24; ++t) {
        if (t + 1 < 24)
            stage(t + 1, (t & 1) ? (char*)As0 : (char*)As1,
                          (t & 1) ? (char*)Bs0 : (char*)Bs1);
        compute((t & 1) ? As1 : As0, (t & 1) ? Bs1 : Bs0);
        VM0; BAR;                 // own prefetch done -> publish buffer
    }

    // ---- epilogue (all float4) ----
    const int colb = bn * 128 + wn + q4 * 4;   // lane's first cb col (i=0)
    float cc[4][4];
    #pragma unroll
    for (int i = 0; i < 4; ++i) {
        float4 t4 = *(const float4*)(c2 + colb + i * 16);
        cc[i][0] = t4.x; cc[i][1] = t4.y; cc[i][2] = t4.z; cc[i][3] = t4.w;
    }

    #pragma unroll
    for (int j = 0; j < 4; ++j) {
        const int prow = bm * 128 + wm + j * 16 + fr;
        const float* nrow = noise + (size_t)prow * KCB + colb;
        float* urow = U + (size_t)prow * KCB + colb;
        float nz[4][4];
        #pragma unroll
        for (int i = 0; i < 4; ++i) {
            float4 t4 = *(const float4*)(nrow + i * 16);
            nz[i][0] = t4.x; nz[i][1] = t4.y; nz[i][2] = t4.z; nz[i][3] = t4.w;
        }
        float sum = 0.f;
        unsigned long long pk = ~0ULL;
        #pragma unroll
        for (int i = 0; i < 4; ++i) {
            float uo[4];
            #pragma unroll
            for (int r = 0; r < 4; ++r) {
                const float xc2 = acc[i][j][r];              // 2*log2e*x.c
                const float tt = xc2 - cc[i][r] + nz[i][r] * LOG2E;
                const float u = exp2f(tt);
                uo[r] = u;
                sum += u;
                const float s = cc[i][r] - xc2;              // monotone in dist
                unsigned int bb = __float_as_uint(s);
                bb = (bb & 0x80000000u) ? ~bb : (bb | 0x80000000u);
                unsigned long long p =
                    ((unsigned long long)bb << 32) | (unsigned int)(colb + i * 16 + r);
                pk = p < pk ? p : pk;
            }
            *(float4*)(urow + i * 16) = make_float4(uo[0], uo[1], uo[2], uo[3]);
        }
        #pragma unroll
        for (int m = 16; m <= 32; m <<= 1) {
            sum += __shfl_xor(sum, m);
            unsigned long long op = __shfl_xor(pk, m);
            pk = op < pk ? op : pk;
        }
        if (lane < 16) {
            atomicAdd(&lsum[wm + j * 16 + fr], sum);
            atomicMin(&lmin[wm + j * 16 + fr], pk);
        }
    }
    __syncthreads();
    if (tid < 128) {
        atomicAdd(&gsum[bm * 128 + tid], lsum[tid]);
        atomicMin(&gmin[bm * 128 + tid], lmin[tid]);
    }
}

// ---- GEMM2 v3: direct-B from L2, A-only LDS, 256-K supersteps ----
// B (chT) has ZERO cross-wave reuse (each wave owns 64 D-rows, each element
// used twice from regs) -> load global->reg, no LDS, no B barriers. chT is
// 4MB = L2-resident. Only A (shared x4 waves) is LDS-staged: 32 supersteps
// of K=256, rows padded to 260 halves (130-word stride -> conflict-free
// b128 reads/writes). T14: U-loads issued one superstep ahead of use;
// barriers are lgkmcnt(0)+s_barrier only, so U prefetch + E stores float.
__global__ __launch_bounds__(256) void gemm2(
    float* __restrict__ U, const f16* __restrict__ chT,
    const float* __restrict__ gsum, const unsigned long long* __restrict__ gmin,
    float* __restrict__ Q, float* __restrict__ IDX)
{
    __shared__ f16 As[2][32 * 260];
    __shared__ float invl[32];

    const int tid = threadIdx.x, lane = tid & 63, wid = tid >> 6;
    const int r0 = blockIdx.x * 32;
    if (tid < 32) {
        invl[tid] = 1.0f / gsum[r0 + tid];
        IDX[r0 + tid] = (float)(unsigned int)(gmin[r0 + tid] & 0xFFFFFFFFull);
    }

    const int arow = tid >> 3;            // 0..31
    const int akc  = (tid & 7) * 32;      // k-offset within superstep
    const int fr = lane & 15, q4 = lane >> 4, fk = q4 * 8;
    const int d0 = wid * 64;

    float* const urow = U + (size_t)(r0 + arow) * KCB + akc;

    const f32x4 z = {0.f, 0.f, 0.f, 0.f};
    f32x4 acc[2][4];
    #pragma unroll
    for (int i = 0; i < 2; ++i)
        #pragma unroll
        for (int j = 0; j < 4; ++j) acc[i][j] = z;

    float4 up[8];                          // prefetched U chunk (32 floats)
    auto uload = [&](int s) {
        #pragma unroll
        for (int c = 0; c < 8; ++c)
            up[c] = *(const float4*)(urow + (size_t)s * 256 + c * 4);
    };
    float il;
    auto stage = [&](int s, f16* asd) {    // consume up -> E store + LDS f16
        #pragma unroll
        for (int c = 0; c < 8; c += 2) {
            float e0 = up[c].x * il,   e1 = up[c].y * il;
            float e2 = up[c].z * il,   e3 = up[c].w * il;
            float e4 = up[c+1].x * il, e5 = up[c+1].y * il;
            float e6 = up[c+1].z * il, e7 = up[c+1].w * il;
            *(float4*)(urow + (size_t)s * 256 + c * 4)     = make_float4(e0, e1, e2, e3);
            *(float4*)(urow + (size_t)s * 256 + c * 4 + 4) = make_float4(e4, e5, e6, e7);
            f16x8 h;
            h[0] = (f16)e0; h[1] = (f16)e1; h[2] = (f16)e2; h[3] = (f16)e3;
            h[4] = (f16)e4; h[5] = (f16)e5; h[6] = (f16)e6; h[7] = (f16)e7;
            *(f16x8*)(asd + arow * 260 + akc + c * 4) = h;
        }
    };
    auto compute = [&](const f16* as_, int s) {
        #pragma unroll
        for (int m = 0; m < 8; ++m) {
            const int kk = m * 32 + fk;
            f16x8 a0 = *(const f16x8*)(as_ + fr * 260 + kk);
            f16x8 a1 = *(const f16x8*)(as_ + (16 + fr) * 260 + kk);
            const size_t kabs = (size_t)s * 256 + kk;
            #pragma unroll
            for (int j = 0; j < 4; ++j) {
                f16x8 bj = *(const f16x8*)(chT + (size_t)(d0 + j * 16 + fr) * KCB + kabs);
                acc[0][j] = __builtin_amdgcn_mfma_f32_16x16x32_f16(a0, bj, acc[0][j], 0, 0, 0);
                acc[1][j] = __builtin_amdgcn_mfma_f32_16x16x32_f16(a1, bj, acc[1][j], 0, 0, 0);
            }
        }
    };

    // prologue
    uload(0);
    __syncthreads();                      // invl visible (drains u(0) too: ok)
    il = invl[arow];
    stage(0, As[0]);
    uload(1);
    LG0; BAR;

    for (int s = 0; s < 32; ++s) {
        if (s + 1 < 32) {
            stage(s + 1, As[(s + 1) & 1]);
            if (s + 2 < 32) uload(s + 2);
        }
        compute(As[s & 1], s);
        LG0; BAR;
    }

    const int rq = q4 * 4;
    #pragma unroll
    for (int i = 0; i < 2; ++i)
        #pragma unroll
        for (int j = 0; j < 4; ++j) {
            const int col = wid * 64 + j * 16 + fr;
            #pragma unroll
            for (int r = 0; r < 4; ++r) {
                const int row = r0 + i * 16 + rq + r;
                Q[row * DDIM + col] = acc[i][j][r];
            }
        }
}

extern "C" void kernel_launch(void* const* d_in, const int* in_sizes, int n_in,
                              void* d_out, int out_size, void* d_ws, size_t ws_size,
                              hipStream_t stream) {
    const float* x     = (const float*)d_in[0];
    const float* cb    = (const float*)d_in[1];
    const float* noise = (const float*)d_in[2];

    float* Q   = (float*)d_out;                       // [16384,256]
    float* E   = Q + 4194304;                         // [16384,8192]
    float* IDX = Q + 138412032;                       // [16384]

    char* ws = (char*)d_ws;
    f16* Acat = (f16*)ws;                             // 25,165,824 B
    f16* Bcat = (f16*)(ws + 25165824);                // 12,582,912 B
    f16* chT  = (f16*)(ws + 37748736);                //  4,194,304 B
    float* c2 = (float*)(ws + 41943040);              //     32,768 B
    float* gsum = (float*)(ws + 41975808);            //     65,536 B
    unsigned long long* gmin =
        (unsigned long long*)(ws + 42041344);         //    131,072 B

    init_k<<<64, 256, 0, stream>>>(gsum, gmin);
    prep_x<<<NPIX, 256, 0, stream>>>(x, Acat);
    prep_c<<<KCB, 256, 0, stream>>>(cb, Bcat, c2);
    transpose_c<<<dim3(128, 4), 256, 0, stream>>>(Bcat, chT);
    gemm1<<<dim3(64, 128), 256, 0, stream>>>(Acat, Bcat, c2, noise, E, gsum, gmin);
    gemm2<<<512, 256, 0, stream>>>(E, chT, gsum, gmin, Q, IDX);
}